// Round 6
// baseline (86.003 us; speedup 1.0000x reference)
//
#include <hip/hip_runtime.h>
#include <math.h>
#include <float.h>

// VQ-VAE quantizer, round 6: barrier-free main loop, MFMA A-operands direct
// from L2 (codebook fp16 = 256 KB, L2-resident), x pre-transposed+split to
// fp16 hi/lo pairs by a memory-bound prep kernel (exact: x = xh + xl in the
// MFMA sum => 2 MFMAs per K-step, identical math to rounds 4-5).
// 1024 blocks x 256 thr; block = 32 points; wave = codebook quarter (256
// codes, 8 chunks of 32). No LDS staging, no mid-loop barriers.
// Packed top-2 per quarter (score bits | 1023-k), exact fp32 rescore of the
// 8 candidates -> argmin (verified hedge, rounds 1-5).

typedef __attribute__((ext_vector_type(8))) _Float16 f16x8;
typedef __attribute__((ext_vector_type(16))) float f32x16;

// vq_main LDS layout
#define QT_OFF    0        // 32 pts * 512 B quantized tile (epilogue)
#define EH2_OFF   16384    // 4 KB: -0.5*|e|^2 all 1024 codes
#define KCND_OFF  20480    // 8*32 ints
#define SCS_OFF   21504    // 8*32 floats
#define KFIN_OFF  22528    // 32 ints
#define WSUM_OFF  22656    // 4 floats
#define SMEM_BYTES 22672

typedef __attribute__((address_space(1))) const void gas_t;
typedef __attribute__((address_space(3))) void las_t;
__device__ __forceinline__ void glds16(const void* g, void* l) {
  __builtin_amdgcn_global_load_lds((gas_t*)g, (las_t*)l, 16, 0, 0);
}

// ---- prep: emb f32 -> eh fp16 [1024][128] + eh2 = -0.5*|e|^2 (f32) ----
__global__ __launch_bounds__(256)
void vq_prep(const float* __restrict__ emb, _Float16* __restrict__ ehg,
             float* __restrict__ eh2g) {
  const int tid = threadIdx.x;
  const int r = blockIdx.x * 16 + (tid >> 4);
  const int seg = tid & 15;
  const float* row = emb + (size_t)r * 128 + seg * 8;
  float4 f0 = *(const float4*)&row[0];
  float4 f1 = *(const float4*)&row[4];
  float fv[8] = {f0.x, f0.y, f0.z, f0.w, f1.x, f1.y, f1.z, f1.w};
  f16x8 H;
  float ssq = 0.f;
#pragma unroll
  for (int j = 0; j < 8; ++j) {
    float f = fv[j];
    ssq = fmaf(f, f, ssq);
    H[j] = (_Float16)f;
  }
  *(f16x8*)(ehg + (size_t)r * 128 + seg * 8) = H;
#pragma unroll
  for (int off = 1; off < 16; off <<= 1) ssq += __shfl_xor(ssq, off, 64);
  if (seg == 0) eh2g[r] = -0.5f * ssq;
}

// ---- prepx: x [16,1,128,2048] f32 -> xth/xtl [32768][128] fp16 (transposed
// split pair). Block = 128 t x 128 d tile, LDS transpose (pad 132). ----
__global__ __launch_bounds__(256)
void vq_prepx(const float* __restrict__ x, _Float16* __restrict__ xth,
              _Float16* __restrict__ xtl) {
  __shared__ float xs[128 * 132];
  const int tid = threadIdx.x;
  const int b = blockIdx.x >> 4;
  const int tt0 = (blockIdx.x & 15) << 7;
  const float* xp = x + (size_t)b * 262144 + tt0;
  for (int i = tid * 4; i < 16384; i += 1024) {
    int dd = i >> 7, tt = i & 127;
    *(float4*)&xs[dd * 132 + tt] = *(const float4*)&xp[(size_t)dd * 2048 + tt];
  }
  __syncthreads();
  const int t = tid >> 1, half = tid & 1;
  const size_t row = ((size_t)b * 2048 + tt0 + t) * 128 + half * 64;
  f16x8 H[8], L[8];
#pragma unroll
  for (int j = 0; j < 64; ++j) {
    float f = xs[(half * 64 + j) * 132 + t];
    _Float16 h = (_Float16)f;
    H[j >> 3][j & 7] = h;
    L[j >> 3][j & 7] = (_Float16)(f - (float)h);
  }
#pragma unroll
  for (int s = 0; s < 8; ++s) {
    *(f16x8*)(xth + row + s * 8) = H[s];
    *(f16x8*)(xtl + row + s * 8) = L[s];
  }
}

template <bool XT>
__global__ __launch_bounds__(256, 4)
void vq_main(const float* __restrict__ x, const float* __restrict__ emb,
             const _Float16* __restrict__ ehg, const float* __restrict__ eh2g,
             const _Float16* __restrict__ xth, const _Float16* __restrict__ xtl,
             float* __restrict__ out, float* __restrict__ partial) {
  __shared__ __align__(16) char smem[SMEM_BYTES];
  float* eh2s = (float*)(smem + EH2_OFF);
  int*   kcnd = (int*)(smem + KCND_OFF);
  float* scs  = (float*)(smem + SCS_OFF);
  int*   kfin = (int*)(smem + KFIN_OFF);
  float* wsum = (float*)(smem + WSUM_OFF);

  const int tid = threadIdx.x;
  const int lane = tid & 63;
  const int w = tid >> 6;          // codebook quarter (256 codes)
  const int hf = lane >> 5;        // K-half of mfma fragment
  const int c32 = lane & 31;       // mfma column = point; also A code row
  const int blk = blockIdx.x;
  const int b = blk >> 6;
  const int t0 = (blk & 63) << 5;  // 32-point tile
  const size_t bOff = (size_t)b * 262144;

  // stage eh2 (4 KB) async; drained by the one pre-loop barrier
  glds16((const char*)eh2g + tid * 16, smem + EH2_OFF + tid * 16);

  // x B-fragments
  f16x8 xh[8], xl[8];
  if (XT) {
    const _Float16* xr = xth + ((size_t)(b * 2048 + t0 + c32)) * 128 + hf * 8;
    const _Float16* xr2 = xtl + ((size_t)(b * 2048 + t0 + c32)) * 128 + hf * 8;
#pragma unroll
    for (int ds = 0; ds < 8; ++ds) {
      xh[ds] = *(const f16x8*)(xr + ds * 16);
      xl[ds] = *(const f16x8*)(xr2 + ds * 16);
    }
  } else {
    const float* xp = x + bOff + t0 + c32;
    const int dbase = hf * 8;
#pragma unroll
    for (int ds = 0; ds < 8; ++ds)
#pragma unroll
      for (int j = 0; j < 8; ++j) {
        float f = xp[(size_t)(ds * 16 + dbase + j) * 2048];
        _Float16 h = (_Float16)f;
        xh[ds][j] = h;
        xl[ds][j] = (_Float16)(f - (float)h);
      }
  }

  __syncthreads();   // eh2 staged

  const float NEG = __uint_as_float(0xFF800000u);   // -inf
  float v1 = NEG, v2 = NEG;

  for (int c = 0; c < 8; ++c) {
    const int kb = w * 256 + c * 32;
    // C-init: acc[reg] = -0.5*|e_k|^2, k = kb + (reg&3) + 8*(reg>>2) + 4*hf
    f32x16 acc;
#pragma unroll
    for (int q = 0; q < 4; ++q) {
      float4 v = *(const float4*)&eh2s[kb + 4 * hf + 8 * q];
      acc[4*q+0] = v.x; acc[4*q+1] = v.y; acc[4*q+2] = v.z; acc[4*q+3] = v.w;
    }
    // A-fragments straight from global (L2-resident 256 KB codebook)
    const _Float16* arow = ehg + (size_t)(kb + c32) * 128 + hf * 8;
    f16x8 e0 = *(const f16x8*)(arow);
#pragma unroll
    for (int ds = 0; ds < 8; ++ds) {
      f16x8 ecur = e0;
      if (ds < 7) e0 = *(const f16x8*)(arow + (ds + 1) * 16);
      acc = __builtin_amdgcn_mfma_f32_32x32x16_f16(ecur, xh[ds], acc, 0, 0, 0);
      acc = __builtin_amdgcn_mfma_f32_32x32x16_f16(ecur, xl[ds], acc, 0, 0, 0);
    }
    // packed top-2: low 10 mantissa bits <- (1023 - k); 2-op insertion
    const int tb = 1023 - kb - 4 * hf;
#pragma unroll
    for (int r = 0; r < 16; ++r) {
      unsigned pc = (unsigned)(tb - ((r & 3) + 8 * (r >> 2)));
      float p = __uint_as_float((__float_as_uint(acc[r]) & 0xFFFFFC00u) | pc);
      float ov1 = v1;
      v1 = fmaxf(v1, p);
      v2 = fmaxf(fminf(p, ov1), v2);
    }
  }

  // merge hf halves -> per-point top-2 of this quarter
  {
    float m1 = __shfl_xor(v1, 32, 64);
    float m2 = __shfl_xor(v2, 32, 64);
    float c1 = fmaxf(v1, m1);
    float c2 = fmaxf(fminf(v1, m1), fmaxf(v2, m2));
    if (hf == 0) {
      kcnd[(w * 2 + 0) * 32 + c32] = 1023 - (int)(__float_as_uint(c1) & 1023u);
      kcnd[(w * 2 + 1) * 32 + c32] = 1023 - (int)(__float_as_uint(c2) & 1023u);
    }
  }
  __syncthreads();

  // exact fp32 rescore of 8 candidates: sc = x.e - |e|^2/2 (maximize)
  {
    const int p = tid & 31, cand = tid >> 5;
    const int kc = kcnd[cand * 32 + p];
    const float* xc = x + bOff + t0 + p;
    const float* er = emb + (size_t)kc * 128;
    float dsum = 0.f;
#pragma unroll 4
    for (int d4 = 0; d4 < 128; d4 += 4) {
      float4 e4 = *(const float4*)&er[d4];
      dsum = fmaf(xc[(size_t)(d4 + 0) * 2048], e4.x, dsum);
      dsum = fmaf(xc[(size_t)(d4 + 1) * 2048], e4.y, dsum);
      dsum = fmaf(xc[(size_t)(d4 + 2) * 2048], e4.z, dsum);
      dsum = fmaf(xc[(size_t)(d4 + 3) * 2048], e4.w, dsum);
    }
    scs[cand * 32 + p] = dsum + eh2s[kc];
  }
  __syncthreads();
  if (tid < 32) {
    float bs = scs[tid]; int bk = kcnd[tid];
#pragma unroll
    for (int cd = 1; cd < 8; ++cd) {
      float v = scs[cd * 32 + tid];
      int k = kcnd[cd * 32 + tid];
      if (v > bs || (v == bs && k < bk)) { bs = v; bk = k; }
    }
    kfin[tid] = bk;
  }
  __syncthreads();

  // E1: gather emb rows -> qt (slot-XOR swizzled)
  {
    const int p = tid >> 3, seg = tid & 7;
    const float* er = emb + (size_t)kfin[p] * 128 + seg * 16;
#pragma unroll
    for (int j = 0; j < 4; ++j) {
      int slot = seg * 4 + j;
      int sw = slot ^ (p & 31);
      *(float4*)(smem + QT_OFF + p * 512 + sw * 16) = *(const float4*)&er[j * 4];
    }
  }
  __syncthreads();

  // E2: lane = point; read qt along d, coalesced stores along t
  float lsum = 0.f;
  {
    const int p = tid & 31, jb = tid >> 5;
    const float* xg = x + bOff + t0 + p;
    float* og = out + bOff + t0 + p;
#pragma unroll
    for (int i = 0; i < 4; ++i) {
      int slot = jb * 4 + i;
      int sw = slot ^ (p & 31);
      float4 q4 = *(const float4*)(smem + QT_OFF + p * 512 + sw * 16);
      float qa[4] = {q4.x, q4.y, q4.z, q4.w};
      int dd = slot * 4;
#pragma unroll
      for (int i2 = 0; i2 < 4; ++i2) {
        float xv = xg[(size_t)(dd + i2) * 2048];
        float df = qa[i2] - xv;
        lsum = fmaf(df, df, lsum);
        og[(size_t)(dd + i2) * 2048] = qa[i2];
      }
    }
  }
#pragma unroll
  for (int off = 32; off; off >>= 1) lsum += __shfl_down(lsum, off, 64);
  if (lane == 0) wsum[w] = lsum;
  __syncthreads();
  if (tid == 0) partial[blk] = (wsum[0] + wsum[1]) + (wsum[2] + wsum[3]);
}

__global__ void vq_loss(const float* __restrict__ partial, float* __restrict__ out) {
  int lane = threadIdx.x;  // 64 threads, 1024 partials
  float s = 0.f;
#pragma unroll
  for (int i = 0; i < 16; ++i) s += partial[i * 64 + lane];
#pragma unroll
  for (int off = 32; off; off >>= 1) s += __shfl_down(s, off, 64);
  if (lane == 0) out[4194304] = 1.25f * s / 4194304.0f;
}

extern "C" void kernel_launch(void* const* d_in, const int* in_sizes, int n_in,
                              void* d_out, int out_size, void* d_ws, size_t ws_size,
                              hipStream_t stream) {
  const float* x   = (const float*)d_in[0];   // [16,1,128,2048]
  const float* emb = (const float*)d_in[1];   // [1024,128]
  float* out = (float*)d_out;
  char* ws = (char*)d_ws;

  const size_t XTH_B = 32768ull * 128 * 2;    // 8 MB each
  const size_t need_big = 2 * XTH_B + 262144 + 4096 + 4096;

  if (ws_size >= need_big) {
    _Float16* xth = (_Float16*)ws;
    _Float16* xtl = (_Float16*)(ws + XTH_B);
    _Float16* ehg = (_Float16*)(ws + 2 * XTH_B);
    float* eh2g = (float*)(ws + 2 * XTH_B + 262144);
    float* partial = (float*)(ws + 2 * XTH_B + 262144 + 4096);
    vq_prep<<<64, 256, 0, stream>>>(emb, ehg, eh2g);
    vq_prepx<<<256, 256, 0, stream>>>(x, xth, xtl);
    vq_main<true><<<1024, 256, 0, stream>>>(x, emb, ehg, eh2g, xth, xtl, out, partial);
    vq_loss<<<1, 64, 0, stream>>>(partial, out);
  } else {
    _Float16* ehg = (_Float16*)ws;
    float* eh2g = (float*)(ws + 262144);
    float* partial = (float*)(ws + 266240);
    vq_prep<<<64, 256, 0, stream>>>(emb, ehg, eh2g);
    vq_main<false><<<1024, 256, 0, stream>>>(x, emb, ehg, eh2g, nullptr, nullptr, out, partial);
    vq_loss<<<1, 64, 0, stream>>>(partial, out);
  }
}